// Round 5
// baseline (31.557 us; speedup 1.0000x reference)
//
#include <hip/hip_runtime.h>

// NODE ensemble forward, round 4 — fully fused GEMM + sigmoid + tree-fold.
//   K1 pack:  fsel fp32 [384][512] -> bf16 MFMA B-frag layout (pk in d_ws)
//   K2 fused: 256 blocks x 512 thr (8 waves, 1 block/CU), 64 rows/block.
//     - B in registers: wave owns 48 cols x K=512 = breg[3][16] (192 VGPRs)
//     - x streamed in 4 tiles of 16 rows via LDS (single buffer, T14
//       reg-prefetch, lgkmcnt-only barriers -> loads stay in flight)
//     - sigmoid probs -> LDS bf16 [64][384] (48 KB)
//     - tail: w[64] into regs (breg dead), fold 8 rows/wave from LDS,
//       shuffle-reduce over 64 trees, out[b]
//
// B=16384, D=512, T=64, DEPTH=6, NCOL=384.

#define DD     512
#define NCOL   384
#define NDEPTH 6

typedef __bf16 bf16_t;
typedef __bf16 bf16x8 __attribute__((ext_vector_type(8)));
typedef float  f32x4  __attribute__((ext_vector_type(4)));

static __device__ __forceinline__ float b2f(unsigned int u16) {
  unsigned int t = u16 << 16;
  float f;
  __builtin_memcpy(&f, &t, 4);
  return f;
}

// pk[((cf*16 + ksg)*64 + lane)*8 + j] = fsel[cf*16+(lane&15)][ksg*32+(lane>>4)*8+j]
__global__ __launch_bounds__(256) void node_pack(const float* __restrict__ fsel,
                                                 bf16_t* __restrict__ pk)
{
  int tid  = blockIdx.x * 256 + threadIdx.x;   // 0..24575
  int lane = tid & 63;
  int ksg  = (tid >> 6) & 15;
  int cf   = tid >> 10;                        // 0..23
  int col  = cf * 16 + (lane & 15);
  int k    = ksg * 32 + (lane >> 4) * 8;
  float4 f0 = *reinterpret_cast<const float4*>(fsel + (size_t)col * DD + k);
  float4 f1 = *reinterpret_cast<const float4*>(fsel + (size_t)col * DD + k + 4);
  bf16x8 v;
  v[0] = (bf16_t)f0.x; v[1] = (bf16_t)f0.y; v[2] = (bf16_t)f0.z; v[3] = (bf16_t)f0.w;
  v[4] = (bf16_t)f1.x; v[5] = (bf16_t)f1.y; v[6] = (bf16_t)f1.z; v[7] = (bf16_t)f1.w;
  *reinterpret_cast<bf16x8*>(pk + (size_t)tid * 8) = v;
}

__global__ __launch_bounds__(512, 2) void node_fused(
    const float*  __restrict__ x,      // [B][512]
    const bf16_t* __restrict__ pk,     // packed B frags
    const float*  __restrict__ thr,    // [384]
    const float*  __restrict__ lw,     // [64][64]
    float*        __restrict__ out)    // [B]
{
  // xf: x-tile (16 rows) in MFMA frag layout: xf[(ks*64+lane)*8 + j]
  // pr: sigmoid probs for all 64 rows of the block, bf16 row-major
  __shared__ bf16_t xf[8192];          // 16 KiB
  __shared__ bf16_t pr[64 * NCOL];     // 48 KiB   (total exactly 64 KiB)

  const int tid  = threadIdx.x;
  const int lane = tid & 63;
  const int wv   = tid >> 6;           // 0..7; wave owns cols wv*48..+47
  const int rowblk = blockIdx.x * 64;
  const int srow = lane & 15;
  const int skg  = lane >> 4;

  // ---- B into registers: 3 col-frags x 16 k-steps, loaded once ----
  bf16x8 breg[3][16];
  #pragma unroll
  for (int f = 0; f < 3; ++f) {
    #pragma unroll
    for (int ks = 0; ks < 16; ++ks) {
      breg[f][ks] = *reinterpret_cast<const bf16x8*>(
          pk + ((size_t)(((wv * 3 + f) * 16 + ks) * 64) + lane) * 8);
    }
  }

  float th[3];
  #pragma unroll
  for (int f = 0; f < 3; ++f) th[f] = thr[wv * 48 + f * 16 + (lane & 15)];

  // staging regs: wave wv covers ks = wv and wv+8 of the 16-row tile
  float4 st[4];

  #define ISSUE_LOADS(t)                                                        \
    do {                                                                        \
      const float* base_ = x + (size_t)(rowblk + (t) * 16 + srow) * DD + skg*8; \
      st[0] = *reinterpret_cast<const float4*>(base_ + wv * 32);                \
      st[1] = *reinterpret_cast<const float4*>(base_ + wv * 32 + 4);            \
      st[2] = *reinterpret_cast<const float4*>(base_ + (wv + 8) * 32);          \
      st[3] = *reinterpret_cast<const float4*>(base_ + (wv + 8) * 32 + 4);      \
    } while (0)

  #define WRITE_LDS()                                                           \
    do {                                                                        \
      bf16x8 v0_, v1_;                                                          \
      v0_[0]=(bf16_t)st[0].x; v0_[1]=(bf16_t)st[0].y;                           \
      v0_[2]=(bf16_t)st[0].z; v0_[3]=(bf16_t)st[0].w;                           \
      v0_[4]=(bf16_t)st[1].x; v0_[5]=(bf16_t)st[1].y;                           \
      v0_[6]=(bf16_t)st[1].z; v0_[7]=(bf16_t)st[1].w;                           \
      v1_[0]=(bf16_t)st[2].x; v1_[1]=(bf16_t)st[2].y;                           \
      v1_[2]=(bf16_t)st[2].z; v1_[3]=(bf16_t)st[2].w;                           \
      v1_[4]=(bf16_t)st[3].x; v1_[5]=(bf16_t)st[3].y;                           \
      v1_[6]=(bf16_t)st[3].z; v1_[7]=(bf16_t)st[3].w;                           \
      *reinterpret_cast<bf16x8*>(&xf[(wv * 64 + lane) * 8])       = v0_;        \
      *reinterpret_cast<bf16x8*>(&xf[((wv + 8) * 64 + lane) * 8]) = v1_;        \
    } while (0)

  ISSUE_LOADS(0);

  // ---- 4 tiles of 16 rows: MFMA + sigmoid -> pr (LDS) ----
  #pragma unroll
  for (int t = 0; t < 4; ++t) {
    WRITE_LDS();                       // vmcnt wait via st reg deps
    if (t < 3) ISSUE_LOADS(t + 1);     // next tile's loads fly during MFMA
    asm volatile("s_waitcnt lgkmcnt(0)" ::: "memory");
    __builtin_amdgcn_s_barrier();      // xf ready for all waves

    f32x4 acc[3];
    #pragma unroll
    for (int f = 0; f < 3; ++f) acc[f] = (f32x4){0.f, 0.f, 0.f, 0.f};

    #pragma unroll
    for (int ks = 0; ks < 16; ++ks) {
      bf16x8 a = *reinterpret_cast<const bf16x8*>(&xf[(ks * 64 + lane) * 8]);
      acc[0] = __builtin_amdgcn_mfma_f32_16x16x32_bf16(a, breg[0][ks], acc[0], 0, 0, 0);
      acc[1] = __builtin_amdgcn_mfma_f32_16x16x32_bf16(a, breg[1][ks], acc[1], 0, 0, 0);
      acc[2] = __builtin_amdgcn_mfma_f32_16x16x32_bf16(a, breg[2][ks], acc[2], 0, 0, 0);
    }

    // sigmoid + store to pr. D layout: row=(lane>>4)*4+r, col=wv*48+f*16+(lane&15)
    #pragma unroll
    for (int f = 0; f < 3; ++f) {
      const int col = wv * 48 + f * 16 + (lane & 15);
      #pragma unroll
      for (int r = 0; r < 4; ++r) {
        const int row = t * 16 + (lane >> 4) * 4 + r;
        float z = acc[f][r] - th[f];
        float p = 1.0f / (1.0f + __expf(-z));
        pr[row * NCOL + col] = (bf16_t)p;
      }
    }

    asm volatile("s_waitcnt lgkmcnt(0)" ::: "memory");
    __builtin_amdgcn_s_barrier();      // xf reads + pr writes done
  }
  #undef ISSUE_LOADS
  #undef WRITE_LDS

  // ---- fold: lane = tree; wave wv folds rows wv*8 .. wv*8+7 ----
  // (breg dead here -> registers reused for w[64])
  float w[64];
  #pragma unroll
  for (int j = 0; j < 16; ++j) {
    float4 f = *reinterpret_cast<const float4*>(lw + (size_t)lane * 64 + j * 4);
    w[4*j] = f.x; w[4*j+1] = f.y; w[4*j+2] = f.z; w[4*j+3] = f.w;
  }

  #pragma unroll
  for (int rr = 0; rr < 8; ++rr) {
    const int row = wv * 8 + rr;
    const unsigned int* prow =
        reinterpret_cast<const unsigned int*>(pr + row * NCOL) + lane * 3;
    unsigned int d0 = prow[0], d1 = prow[1], d2 = prow[2];
    float p[NDEPTH];
    p[0] = b2f(d0 & 0xffffu); p[1] = b2f(d0 >> 16);
    p[2] = b2f(d1 & 0xffffu); p[3] = b2f(d1 >> 16);
    p[4] = b2f(d2 & 0xffffu); p[5] = b2f(d2 >> 16);

    float v[32];
    #pragma unroll
    for (int j = 0; j < 32; ++j) v[j] = fmaf(p[5], w[2*j] - w[2*j+1], w[2*j+1]);
    #pragma unroll
    for (int j = 0; j < 16; ++j) v[j] = fmaf(p[4], v[2*j] - v[2*j+1], v[2*j+1]);
    #pragma unroll
    for (int j = 0; j < 8;  ++j) v[j] = fmaf(p[3], v[2*j] - v[2*j+1], v[2*j+1]);
    #pragma unroll
    for (int j = 0; j < 4;  ++j) v[j] = fmaf(p[2], v[2*j] - v[2*j+1], v[2*j+1]);
    #pragma unroll
    for (int j = 0; j < 2;  ++j) v[j] = fmaf(p[1], v[2*j] - v[2*j+1], v[2*j+1]);
    float tv = fmaf(p[0], v[0] - v[1], v[1]);

    #pragma unroll
    for (int off = 32; off; off >>= 1) tv += __shfl_xor(tv, off, 64);
    if (lane == 0) out[rowblk + row] = tv;
  }
}

extern "C" void kernel_launch(void* const* d_in, const int* in_sizes, int n_in,
                              void* d_out, int out_size, void* d_ws, size_t ws_size,
                              hipStream_t stream) {
  const float* x    = (const float*)d_in[0];
  const float* fsel = (const float*)d_in[1];
  const float* thr  = (const float*)d_in[2];
  const float* lw   = (const float*)d_in[3];
  float* out = (float*)d_out;

  bf16_t* pk = (bf16_t*)d_ws;                 // 393216 B

  const int B = in_sizes[0] / DD;             // 16384

  node_pack<<<dim3(96), dim3(256), 0, stream>>>(fsel, pk);
  node_fused<<<dim3(B / 64), dim3(512), 0, stream>>>(x, pk, thr, lw, out);
}